// Round 4
// baseline (6913.907 us; speedup 1.0000x reference)
//
#include <hip/hip_runtime.h>

#define BN_EPS 1e-5f

__device__ __forceinline__ void atomicAdd4(float* p, float4 v) {
    unsafeAtomicAdd(p + 0, v.x);
    unsafeAtomicAdd(p + 1, v.y);
    unsafeAtomicAdd(p + 2, v.z);
    unsafeAtomicAdd(p + 3, v.w);
}

__device__ __forceinline__ float bnr1(float a, float b, float v) {
    return fmaxf(fmaf(a, v, b), 0.0f);
}

// ===================== CSR build (once, reused for all 4 layers) ============

__global__ __launch_bounds__(256) void k_count(const int* __restrict__ dst,
        int* __restrict__ deg, int nedges)
{
    int e = blockIdx.x * 256 + threadIdx.x;
    if (e < nedges) atomicAdd(&deg[dst[e]], 1);
}

__global__ __launch_bounds__(256) void k_scanA(const int* __restrict__ deg,
        int* __restrict__ incl, int* __restrict__ bsum, int N)
{
    __shared__ int tmp[256];
    int i = blockIdx.x * 256 + threadIdx.x;
    int d = (i < N) ? deg[i] : 0;
    tmp[threadIdx.x] = d;
    __syncthreads();
    for (int off = 1; off < 256; off <<= 1) {
        int val = (threadIdx.x >= off) ? tmp[threadIdx.x - off] : 0;
        __syncthreads();
        tmp[threadIdx.x] += val;
        __syncthreads();
    }
    if (i < N) incl[i] = tmp[threadIdx.x];
    if (threadIdx.x == 255) bsum[blockIdx.x] = tmp[255];
}

__global__ __launch_bounds__(512) void k_scanB(int* __restrict__ bsum, int NB)
{
    __shared__ int tmp[512];
    int tid = threadIdx.x;
    int d = (tid < NB) ? bsum[tid] : 0;
    tmp[tid] = d;
    __syncthreads();
    for (int off = 1; off < 512; off <<= 1) {
        int val = (tid >= off) ? tmp[tid - off] : 0;
        __syncthreads();
        tmp[tid] += val;
        __syncthreads();
    }
    if (tid < NB) bsum[tid] = tmp[tid] - d;   // exclusive
}

__global__ __launch_bounds__(256) void k_scanC(const int* __restrict__ deg,
        const int* __restrict__ incl, const int* __restrict__ bsum,
        int* __restrict__ rowptr, int* __restrict__ fill, int N)
{
    int i = blockIdx.x * 256 + threadIdx.x;
    if (i >= N) return;
    int d = deg[i];
    int excl = incl[i] - d + bsum[blockIdx.x];
    rowptr[i] = excl;
    fill[i] = excl;
    if (i == N - 1) rowptr[N] = excl + d;
}

__global__ __launch_bounds__(256) void k_fill(const int* __restrict__ src,
        const int* __restrict__ dst, int* __restrict__ fill,
        int* __restrict__ csr, int nedges)
{
    int e = blockIdx.x * 256 + threadIdx.x;
    if (e >= nedges) return;
    int pos = atomicAdd(&fill[dst[e]], 1);
    csr[pos] = src[e];
}

// ===================== gather: BN2(prev)+ReLU fused on read =================
// in-row value: layer 0 -> raw x; else relu(a*Z+b) with a,b from Sin stats.
// U[d] = (1+eps)*val(d) + sum_{s in adj(d)} val(s)
// wave = 1 node; lane = (sub 0..3, quad 0..15); float4 per lane.
// NOTE: control flow around every __shfl is wave-uniform (nIter depends only
// on n, which is per-node == per-wave). Shuffle source lane is clamped to a
// valid active lane; only the accumulate is predicated.
__global__ __launch_bounds__(256) void k_gather(const float4* __restrict__ H,
        const int* __restrict__ rowptr, const int* __restrict__ csr,
        const float* __restrict__ Sin, const float* __restrict__ g,
        const float* __restrict__ bt, const float* __restrict__ epsp,
        int layer, float4* __restrict__ U, int N, float invM)
{
    int lane = threadIdx.x & 63;
    int wv = threadIdx.x >> 6;
    int node = blockIdx.x * 4 + wv;
    if (node >= N) return;
    int q = lane & 15, sub = lane >> 4;

    float4 A4 = make_float4(1.f, 1.f, 1.f, 1.f);
    float4 B4 = make_float4(0.f, 0.f, 0.f, 0.f);
    bool dobn = (Sin != nullptr);
    if (dobn) {
        float as[4], bs[4];
#pragma unroll
        for (int j = 0; j < 4; ++j) {
            int c = q * 4 + j;
            float mu = Sin[c] * invM;
            float var = Sin[64 + c] * invM - mu * mu;
            float a = g[c] * rsqrtf(var + BN_EPS);
            as[j] = a;
            bs[j] = bt[c] - a * mu;
        }
        A4 = make_float4(as[0], as[1], as[2], as[3]);
        B4 = make_float4(bs[0], bs[1], bs[2], bs[3]);
    }

    int start = rowptr[node], end = rowptr[node + 1];
    float4 acc = make_float4(0.f, 0.f, 0.f, 0.f);

    for (int base = start; base < end; base += 64) {
        int n = min(64, end - base);               // wave-uniform
        int myidx = (lane < n) ? csr[base + lane] : 0;
        int nIter = (n + 7) >> 3;                  // wave-uniform trip count
        for (int t = 0; t < nIter; ++t) {
            int j0 = t * 8 + sub;
            int j1 = t * 8 + 4 + sub;
            int s0 = __shfl(myidx, (j0 < n) ? j0 : 0);
            int s1 = __shfl(myidx, (j1 < n) ? j1 : 0);
            float4 v0 = H[(size_t)s0 * 16 + q];
            float4 v1 = H[(size_t)s1 * 16 + q];
            if (dobn) {
                v0.x = bnr1(A4.x, B4.x, v0.x); v0.y = bnr1(A4.y, B4.y, v0.y);
                v0.z = bnr1(A4.z, B4.z, v0.z); v0.w = bnr1(A4.w, B4.w, v0.w);
                v1.x = bnr1(A4.x, B4.x, v1.x); v1.y = bnr1(A4.y, B4.y, v1.y);
                v1.z = bnr1(A4.z, B4.z, v1.z); v1.w = bnr1(A4.w, B4.w, v1.w);
            }
            if (j0 < n) {
                acc.x += v0.x; acc.y += v0.y; acc.z += v0.z; acc.w += v0.w;
            }
            if (j1 < n) {
                acc.x += v1.x; acc.y += v1.y; acc.z += v1.z; acc.w += v1.w;
            }
        }
    }
    // reduce across the 4 edge-subgroups (lanes ^16, ^32)
    acc.x += __shfl_xor(acc.x, 16); acc.y += __shfl_xor(acc.y, 16);
    acc.z += __shfl_xor(acc.z, 16); acc.w += __shfl_xor(acc.w, 16);
    acc.x += __shfl_xor(acc.x, 32); acc.y += __shfl_xor(acc.y, 32);
    acc.z += __shfl_xor(acc.z, 32); acc.w += __shfl_xor(acc.w, 32);

    if (sub == 0) {
        float4 hv = H[(size_t)node * 16 + q];
        if (dobn) {
            hv.x = bnr1(A4.x, B4.x, hv.x); hv.y = bnr1(A4.y, B4.y, hv.y);
            hv.z = bnr1(A4.z, B4.z, hv.z); hv.w = bnr1(A4.w, B4.w, hv.w);
        }
        float e = 1.0f + epsp[layer];
        float4 o;
        o.x = fmaf(e, hv.x, acc.x); o.y = fmaf(e, hv.y, acc.y);
        o.z = fmaf(e, hv.z, acc.z); o.w = fmaf(e, hv.w, acc.w);
        U[(size_t)node * 16 + q] = o;
    }
}

// ===================== GEMM: optional BN1+ReLU on input, 2 rows/thread ======
// Out[r][c] = sum_k f(In[r][k]) * W[k][c] + bias[c],  f = relu(a*v+b) or id
__global__ __launch_bounds__(256) void k_gemm(const float4* __restrict__ In,
        const float* __restrict__ Sin, const float* __restrict__ g,
        const float* __restrict__ bt, const float* __restrict__ W,
        const float* __restrict__ bias, float4* __restrict__ Out, int M)
{
    __shared__ float4 Bs[64][16];   // W tile, 16 KB
    __shared__ float As_[64];
    __shared__ float Bb_[64];
    int tid = threadIdx.x;
    const float4* W4 = (const float4*)W;
#pragma unroll
    for (int i = 0; i < 4; ++i)
        ((float4*)Bs)[tid + 256 * i] = W4[tid + 256 * i];
    if (tid < 64) {
        if (Sin) {
            float invM = 1.0f / (float)M;
            float mu = Sin[tid] * invM;
            float var = Sin[64 + tid] * invM - mu * mu;
            float a = g[tid] * rsqrtf(var + BN_EPS);
            As_[tid] = a;
            Bb_[tid] = bt[tid] - a * mu;
        } else { As_[tid] = 1.f; Bb_[tid] = 0.f; }
    }
    __syncthreads();

    int ch = tid & 1;              // column half: cols [32*ch, 32*ch+32)
    int rp = tid >> 1;             // row pair index 0..127
    int row0 = blockIdx.x * 256 + rp * 2;
    if (row0 >= M) return;
    bool r1ok = (row0 + 1) < M;
    bool dobn = (Sin != nullptr);

    const float4* p0 = In + (size_t)row0 * 16;
    const float4* p1 = In + (size_t)(row0 + (r1ok ? 1 : 0)) * 16;

    float4 acc0[8], acc1[8];
    const float4* b4 = (const float4*)bias;
#pragma unroll
    for (int c = 0; c < 8; ++c) { acc0[c] = b4[ch * 8 + c]; acc1[c] = b4[ch * 8 + c]; }

#pragma unroll
    for (int kc = 0; kc < 4; ++kc) {
        float u0[16], u1[16];
#pragma unroll
        for (int j = 0; j < 4; ++j) {
            float4 h0 = p0[kc * 4 + j];
            float4 h1 = p1[kc * 4 + j];
            int kb = kc * 16 + j * 4;
            if (dobn) {
                u0[j*4+0] = bnr1(As_[kb+0], Bb_[kb+0], h0.x);
                u0[j*4+1] = bnr1(As_[kb+1], Bb_[kb+1], h0.y);
                u0[j*4+2] = bnr1(As_[kb+2], Bb_[kb+2], h0.z);
                u0[j*4+3] = bnr1(As_[kb+3], Bb_[kb+3], h0.w);
                u1[j*4+0] = bnr1(As_[kb+0], Bb_[kb+0], h1.x);
                u1[j*4+1] = bnr1(As_[kb+1], Bb_[kb+1], h1.y);
                u1[j*4+2] = bnr1(As_[kb+2], Bb_[kb+2], h1.z);
                u1[j*4+3] = bnr1(As_[kb+3], Bb_[kb+3], h1.w);
            } else {
                u0[j*4+0] = h0.x; u0[j*4+1] = h0.y; u0[j*4+2] = h0.z; u0[j*4+3] = h0.w;
                u1[j*4+0] = h1.x; u1[j*4+1] = h1.y; u1[j*4+2] = h1.z; u1[j*4+3] = h1.w;
            }
        }
#pragma unroll
        for (int k = 0; k < 16; ++k) {
            int kk = kc * 16 + k;
            float a0 = u0[k], a1 = u1[k];
#pragma unroll
            for (int c = 0; c < 8; ++c) {
                float4 bv = Bs[kk][ch * 8 + c];
                acc0[c].x += a0 * bv.x; acc0[c].y += a0 * bv.y;
                acc0[c].z += a0 * bv.z; acc0[c].w += a0 * bv.w;
                acc1[c].x += a1 * bv.x; acc1[c].y += a1 * bv.y;
                acc1[c].z += a1 * bv.z; acc1[c].w += a1 * bv.w;
            }
        }
    }
    float4* o0 = Out + (size_t)row0 * 16 + ch * 8;
#pragma unroll
    for (int c = 0; c < 8; ++c) o0[c] = acc0[c];
    if (r1ok) {
        float4* o1 = Out + (size_t)(row0 + 1) * 16 + ch * 8;
#pragma unroll
        for (int c = 0; c < 8; ++c) o1[c] = acc1[c];
    }
}

// -------- column stats: S[0..63]=sum, S[64..127]=sumsq ----------------------
__global__ __launch_bounds__(256) void k_stats(const float4* __restrict__ V,
        float* __restrict__ S, int M)
{
    int tid = threadIdx.x;
    int q = tid & 15, rs = tid >> 4;
    float4 sum = make_float4(0.f, 0.f, 0.f, 0.f);
    float4 ss = make_float4(0.f, 0.f, 0.f, 0.f);
    for (int r = blockIdx.x * 16 + rs; r < M; r += gridDim.x * 16) {
        float4 v = V[(size_t)r * 16 + q];
        sum.x += v.x; sum.y += v.y; sum.z += v.z; sum.w += v.w;
        ss.x += v.x * v.x; ss.y += v.y * v.y; ss.z += v.z * v.z; ss.w += v.w * v.w;
    }
    sum.x += __shfl_xor(sum.x, 16); sum.y += __shfl_xor(sum.y, 16);
    sum.z += __shfl_xor(sum.z, 16); sum.w += __shfl_xor(sum.w, 16);
    ss.x += __shfl_xor(ss.x, 16);   ss.y += __shfl_xor(ss.y, 16);
    ss.z += __shfl_xor(ss.z, 16);   ss.w += __shfl_xor(ss.w, 16);
    sum.x += __shfl_xor(sum.x, 32); sum.y += __shfl_xor(sum.y, 32);
    sum.z += __shfl_xor(sum.z, 32); sum.w += __shfl_xor(sum.w, 32);
    ss.x += __shfl_xor(ss.x, 32);   ss.y += __shfl_xor(ss.y, 32);
    ss.z += __shfl_xor(ss.z, 32);   ss.w += __shfl_xor(ss.w, 32);

    __shared__ float4 LS[4][16];
    __shared__ float4 LQ[4][16];
    int wave = tid >> 6, lane = tid & 63;
    if (lane < 16) { LS[wave][lane] = sum; LQ[wave][lane] = ss; }
    __syncthreads();
    if (tid < 16) {
        float4 s0 = LS[0][tid], q0 = LQ[0][tid];
#pragma unroll
        for (int w = 1; w < 4; ++w) {
            float4 sw = LS[w][tid], qw = LQ[w][tid];
            s0.x += sw.x; s0.y += sw.y; s0.z += sw.z; s0.w += sw.w;
            q0.x += qw.x; q0.y += qw.y; q0.z += qw.z; q0.w += qw.w;
        }
        atomicAdd4(S + tid * 4, s0);
        atomicAdd4(S + 64 + tid * 4, q0);
    }
}

// -------- per-graph mean pool with BN2+ReLU fused on read -------------------
__global__ __launch_bounds__(256) void k_pool(const float4* __restrict__ H,
        const int* __restrict__ batch, const float* __restrict__ Sin,
        const float* __restrict__ g, const float* __restrict__ bt,
        float* __restrict__ POOL, float* __restrict__ CNT,
        int M, int chunk, float invM)
{
    int q = threadIdx.x & 15, rs = threadIdx.x >> 4;
    float as[4], bs[4];
#pragma unroll
    for (int j = 0; j < 4; ++j) {
        int c = q * 4 + j;
        float mu = Sin[c] * invM;
        float var = Sin[64 + c] * invM - mu * mu;
        float a = g[c] * rsqrtf(var + BN_EPS);
        as[j] = a;
        bs[j] = bt[c] - a * mu;
    }
    int start = blockIdx.x * chunk;
    int end = min(M, start + chunk);
    int curg = -1;
    float4 acc = make_float4(0.f, 0.f, 0.f, 0.f);
    float cl = 0.f;
    for (int r = start + rs; r < end; r += 16) {
        int gg = batch[r];
        float4 v = H[(size_t)r * 16 + q];
        v.x = bnr1(as[0], bs[0], v.x); v.y = bnr1(as[1], bs[1], v.y);
        v.z = bnr1(as[2], bs[2], v.z); v.w = bnr1(as[3], bs[3], v.w);
        if (gg != curg) {
            if (curg >= 0) {
                atomicAdd4(POOL + (size_t)curg * 64 + q * 4, acc);
                if (q == 0) unsafeAtomicAdd(CNT + curg, cl);
            }
            curg = gg;
            acc = make_float4(0.f, 0.f, 0.f, 0.f);
            cl = 0.f;
        }
        acc.x += v.x; acc.y += v.y; acc.z += v.z; acc.w += v.w;
        cl += 1.f;
    }
    if (curg >= 0) {
        atomicAdd4(POOL + (size_t)curg * 64 + q * 4, acc);
        if (q == 0) unsafeAtomicAdd(CNT + curg, cl);
    }
}

// -------- head --------------------------------------------------------------
__global__ __launch_bounds__(256) void k_head(const float* __restrict__ POOL,
        const float* __restrict__ CNT, const float* __restrict__ Wh,
        const float* __restrict__ bh, float* __restrict__ OUT, int ngraph)
{
    int lane = threadIdx.x & 63;
    int wv = threadIdx.x >> 6;
    int gidx = blockIdx.x * 4 + wv;
    if (gidx >= ngraph) return;
    float c = fmaxf(CNT[gidx], 1.0f);
    float v = POOL[(size_t)gidx * 64 + lane] / c * Wh[lane];
#pragma unroll
    for (int off = 1; off < 64; off <<= 1) v += __shfl_xor(v, off);
    if (lane == 0) OUT[gidx] = v + bh[0];
}

extern "C" void kernel_launch(void* const* d_in, const int* in_sizes, int n_in,
                              void* d_out, int out_size, void* d_ws, size_t ws_size,
                              hipStream_t stream)
{
    const float* x   = (const float*)d_in[0];
    const int*   ei  = (const int*)d_in[1];
    const int*   bat = (const int*)d_in[2];
    const float* W1  = (const float*)d_in[3];
    const float* b1  = (const float*)d_in[4];
    const float* g1  = (const float*)d_in[5];
    const float* bt1 = (const float*)d_in[6];
    const float* W2  = (const float*)d_in[7];
    const float* b2  = (const float*)d_in[8];
    const float* g2  = (const float*)d_in[9];
    const float* bt2 = (const float*)d_in[10];
    const float* eps = (const float*)d_in[11];
    const float* Wh  = (const float*)d_in[12];
    const float* bh  = (const float*)d_in[13];
    float* out = (float*)d_out;

    int M = in_sizes[0] / 64;
    int nedges = in_sizes[1] / 2;
    const int* src = ei;
    const int* dst = ei + nedges;
    const int NG = 512;
    float invM = 1.0f / (float)M;

    float* ws = (float*)d_ws;
    size_t NE = (size_t)M * 64;
    float* P0   = ws;               // U/Z ping
    float* P1   = ws + NE;          // U/Z pong
    float* V    = ws + 2 * NE;
    float* S1   = ws + 3 * NE;      // 4 layers x 128
    float* S2   = S1 + 512;
    float* POOL = S2 + 512;         // 512 x 64
    float* CNT  = POOL + (size_t)NG * 64;  // 512

    int* rowptr = (int*)(CNT + NG);        // M+1
    int* fillp  = rowptr + (M + 1);        // M
    int* deg    = fillp + M;               // M
    int* incl   = deg + M;                 // M
    int* bsum   = incl + M;                // 512
    int* csr    = bsum + 512;              // nedges

    hipMemsetAsync(deg, 0, (size_t)M * sizeof(int), stream);
    hipMemsetAsync(S1, 0, (512 + 512 + (size_t)NG * 64 + NG) * sizeof(float), stream);

    int edgeGrid = (nedges + 255) / 256;

    // ---- CSR build ----
    k_count<<<edgeGrid, 256, 0, stream>>>(dst, deg, nedges);
    int NB = (M + 255) / 256;
    k_scanA<<<NB, 256, 0, stream>>>(deg, incl, bsum, M);
    k_scanB<<<1, 512, 0, stream>>>(bsum, NB);
    k_scanC<<<NB, 256, 0, stream>>>(deg, incl, bsum, rowptr, fillp, M);
    k_fill<<<edgeGrid, 256, 0, stream>>>(src, dst, fillp, csr, nedges);

    int gemmGrid = (M + 255) / 256;
    int gatherGrid = (M + 3) / 4;

    const float* prevZ = x;
    for (int i = 0; i < 4; ++i) {
        float* Ub = (i & 1) ? P1 : P0;
        const float* Sprev = (i == 0) ? nullptr : (S2 + (size_t)(i - 1) * 128);
        const float* gprev = (i == 0) ? g2 : (g2 + (size_t)(i - 1) * 64);
        const float* bprev = (i == 0) ? bt2 : (bt2 + (size_t)(i - 1) * 64);

        k_gather<<<gatherGrid, 256, 0, stream>>>((const float4*)prevZ, rowptr, csr,
                Sprev, gprev, bprev, eps, i, (float4*)Ub, M, invM);
        k_gemm<<<gemmGrid, 256, 0, stream>>>((const float4*)Ub, nullptr, g1, bt1,
                W1 + (size_t)i * 4096, b1 + i * 64, (float4*)V, M);
        k_stats<<<400, 256, 0, stream>>>((const float4*)V, S1 + (size_t)i * 128, M);
        k_gemm<<<gemmGrid, 256, 0, stream>>>((const float4*)V, S1 + (size_t)i * 128,
                g1 + i * 64, bt1 + i * 64, W2 + (size_t)i * 4096, b2 + i * 64,
                (float4*)Ub, M);   // Z overwrites U (dead)
        k_stats<<<400, 256, 0, stream>>>((const float4*)Ub, S2 + (size_t)i * 128, M);
        prevZ = Ub;
    }
    int chunk = (M + 511) / 512;
    k_pool<<<512, 256, 0, stream>>>((const float4*)prevZ, bat, S2 + 3 * 128,
            g2 + 192, bt2 + 192, POOL, CNT, M, chunk, invM);
    k_head<<<(NG + 3) / 4, 256, 0, stream>>>(POOL, CNT, Wh, bh, out, NG);
}

// Round 5
// 1057.659 us; speedup vs baseline: 6.5370x; 6.5370x over previous
//
#include <hip/hip_runtime.h>

#define BN_EPS 1e-5f

__device__ __forceinline__ void atomicAdd4(float* p, float4 v) {
    unsafeAtomicAdd(p + 0, v.x);
    unsafeAtomicAdd(p + 1, v.y);
    unsafeAtomicAdd(p + 2, v.z);
    unsafeAtomicAdd(p + 3, v.w);
}

__device__ __forceinline__ float bnr1(float a, float b, float v) {
    return fmaxf(fmaf(a, v, b), 0.0f);
}

// ===================== CSR build (once, reused for all 4 layers) ============

__global__ __launch_bounds__(256) void k_count(const int* __restrict__ dst,
        int* __restrict__ deg, int nedges)
{
    int e = blockIdx.x * 256 + threadIdx.x;
    if (e < nedges) atomicAdd(&deg[dst[e]], 1);
}

__global__ __launch_bounds__(256) void k_scanA(const int* __restrict__ deg,
        int* __restrict__ incl, int* __restrict__ bsum, int N)
{
    __shared__ int tmp[256];
    int i = blockIdx.x * 256 + threadIdx.x;
    int d = (i < N) ? deg[i] : 0;
    tmp[threadIdx.x] = d;
    __syncthreads();
    for (int off = 1; off < 256; off <<= 1) {
        int val = (threadIdx.x >= off) ? tmp[threadIdx.x - off] : 0;
        __syncthreads();
        tmp[threadIdx.x] += val;
        __syncthreads();
    }
    if (i < N) incl[i] = tmp[threadIdx.x];
    if (threadIdx.x == 255) bsum[blockIdx.x] = tmp[255];
}

__global__ __launch_bounds__(512) void k_scanB(int* __restrict__ bsum, int NB)
{
    __shared__ int tmp[512];
    int tid = threadIdx.x;
    int d = (tid < NB) ? bsum[tid] : 0;
    tmp[tid] = d;
    __syncthreads();
    for (int off = 1; off < 512; off <<= 1) {
        int val = (tid >= off) ? tmp[tid - off] : 0;
        __syncthreads();
        tmp[tid] += val;
        __syncthreads();
    }
    if (tid < NB) bsum[tid] = tmp[tid] - d;   // exclusive
}

__global__ __launch_bounds__(256) void k_scanC(const int* __restrict__ deg,
        const int* __restrict__ incl, const int* __restrict__ bsum,
        int* __restrict__ rowptr, int* __restrict__ fill, int N)
{
    int i = blockIdx.x * 256 + threadIdx.x;
    if (i >= N) return;
    int d = deg[i];
    int excl = incl[i] - d + bsum[blockIdx.x];
    rowptr[i] = excl;
    fill[i] = excl;
    if (i == N - 1) rowptr[N] = excl + d;
}

__global__ __launch_bounds__(256) void k_fill(const int* __restrict__ src,
        const int* __restrict__ dst, int* __restrict__ fill,
        int* __restrict__ csr, int nedges)
{
    int e = blockIdx.x * 256 + threadIdx.x;
    if (e >= nedges) return;
    int pos = atomicAdd(&fill[dst[e]], 1);
    csr[pos] = src[e];
}

// ===================== gather: BN2(prev)+ReLU fused on read =================
// (unchanged from R4 passing version)
__global__ __launch_bounds__(256) void k_gather(const float4* __restrict__ H,
        const int* __restrict__ rowptr, const int* __restrict__ csr,
        const float* __restrict__ Sin, const float* __restrict__ g,
        const float* __restrict__ bt, const float* __restrict__ epsp,
        int layer, float4* __restrict__ U, int N, float invM)
{
    int lane = threadIdx.x & 63;
    int wv = threadIdx.x >> 6;
    int node = blockIdx.x * 4 + wv;
    if (node >= N) return;
    int q = lane & 15, sub = lane >> 4;

    float4 A4 = make_float4(1.f, 1.f, 1.f, 1.f);
    float4 B4 = make_float4(0.f, 0.f, 0.f, 0.f);
    bool dobn = (Sin != nullptr);
    if (dobn) {
        float as[4], bs[4];
#pragma unroll
        for (int j = 0; j < 4; ++j) {
            int c = q * 4 + j;
            float mu = Sin[c] * invM;
            float var = Sin[64 + c] * invM - mu * mu;
            float a = g[c] * rsqrtf(var + BN_EPS);
            as[j] = a;
            bs[j] = bt[c] - a * mu;
        }
        A4 = make_float4(as[0], as[1], as[2], as[3]);
        B4 = make_float4(bs[0], bs[1], bs[2], bs[3]);
    }

    int start = rowptr[node], end = rowptr[node + 1];
    float4 acc = make_float4(0.f, 0.f, 0.f, 0.f);

    for (int base = start; base < end; base += 64) {
        int n = min(64, end - base);               // wave-uniform
        int myidx = (lane < n) ? csr[base + lane] : 0;
        int nIter = (n + 7) >> 3;                  // wave-uniform trip count
        for (int t = 0; t < nIter; ++t) {
            int j0 = t * 8 + sub;
            int j1 = t * 8 + 4 + sub;
            int s0 = __shfl(myidx, (j0 < n) ? j0 : 0);
            int s1 = __shfl(myidx, (j1 < n) ? j1 : 0);
            float4 v0 = H[(size_t)s0 * 16 + q];
            float4 v1 = H[(size_t)s1 * 16 + q];
            if (dobn) {
                v0.x = bnr1(A4.x, B4.x, v0.x); v0.y = bnr1(A4.y, B4.y, v0.y);
                v0.z = bnr1(A4.z, B4.z, v0.z); v0.w = bnr1(A4.w, B4.w, v0.w);
                v1.x = bnr1(A4.x, B4.x, v1.x); v1.y = bnr1(A4.y, B4.y, v1.y);
                v1.z = bnr1(A4.z, B4.z, v1.z); v1.w = bnr1(A4.w, B4.w, v1.w);
            }
            if (j0 < n) {
                acc.x += v0.x; acc.y += v0.y; acc.z += v0.z; acc.w += v0.w;
            }
            if (j1 < n) {
                acc.x += v1.x; acc.y += v1.y; acc.z += v1.z; acc.w += v1.w;
            }
        }
    }
    acc.x += __shfl_xor(acc.x, 16); acc.y += __shfl_xor(acc.y, 16);
    acc.z += __shfl_xor(acc.z, 16); acc.w += __shfl_xor(acc.w, 16);
    acc.x += __shfl_xor(acc.x, 32); acc.y += __shfl_xor(acc.y, 32);
    acc.z += __shfl_xor(acc.z, 32); acc.w += __shfl_xor(acc.w, 32);

    if (sub == 0) {
        float4 hv = H[(size_t)node * 16 + q];
        if (dobn) {
            hv.x = bnr1(A4.x, B4.x, hv.x); hv.y = bnr1(A4.y, B4.y, hv.y);
            hv.z = bnr1(A4.z, B4.z, hv.z); hv.w = bnr1(A4.w, B4.w, hv.w);
        }
        float e = 1.0f + epsp[layer];
        float4 o;
        o.x = fmaf(e, hv.x, acc.x); o.y = fmaf(e, hv.y, acc.y);
        o.z = fmaf(e, hv.z, acc.z); o.w = fmaf(e, hv.w, acc.w);
        U[(size_t)node * 16 + q] = o;
    }
}

// ===================== GEMM: 2 rows x 16 cols per thread ====================
// Out[r][c] = sum_k f(In[r][k]) * W[k][c] + bias[c],  f = relu(a*v+b) or id
// ch = tid&3 selects float4-col group [ch*4, ch*4+4); rp = tid>>2 row pair.
// Block covers 128 rows. kc loop NOT unrolled (caps register pressure; the
// R4 version fully unrolled, hoisted ~128 floats of loads -> 256 VGPR + spill).
__global__ __launch_bounds__(256) void k_gemm(const float4* __restrict__ In,
        const float* __restrict__ Sin, const float* __restrict__ g,
        const float* __restrict__ bt, const float* __restrict__ W,
        const float* __restrict__ bias, float4* __restrict__ Out, int M)
{
    __shared__ float4 Bs[64][16];   // W tile, 16 KB
    __shared__ float As_[64];
    __shared__ float Bb_[64];
    int tid = threadIdx.x;
    const float4* W4 = (const float4*)W;
#pragma unroll
    for (int i = 0; i < 4; ++i)
        ((float4*)Bs)[tid + 256 * i] = W4[tid + 256 * i];
    if (tid < 64) {
        if (Sin) {
            float invM = 1.0f / (float)M;
            float mu = Sin[tid] * invM;
            float var = Sin[64 + tid] * invM - mu * mu;
            float a = g[tid] * rsqrtf(var + BN_EPS);
            As_[tid] = a;
            Bb_[tid] = bt[tid] - a * mu;
        } else { As_[tid] = 1.f; Bb_[tid] = 0.f; }
    }
    __syncthreads();

    int ch = tid & 3;              // col group: float4 cols [ch*4, ch*4+4)
    int rp = tid >> 2;             // row pair index 0..63
    int row0 = blockIdx.x * 128 + rp * 2;
    if (row0 >= M) return;
    bool r1ok = (row0 + 1) < M;
    bool dobn = (Sin != nullptr);

    const float4* p0 = In + (size_t)row0 * 16;
    const float4* p1 = In + (size_t)(row0 + (r1ok ? 1 : 0)) * 16;

    float4 acc0[4], acc1[4];
    const float4* b4 = (const float4*)bias;
#pragma unroll
    for (int c = 0; c < 4; ++c) { acc0[c] = b4[ch * 4 + c]; acc1[c] = acc0[c]; }

#pragma unroll 1
    for (int kc = 0; kc < 4; ++kc) {
        float u0[16], u1[16];
#pragma unroll
        for (int j = 0; j < 4; ++j) {
            float4 h0 = p0[kc * 4 + j];
            float4 h1 = p1[kc * 4 + j];
            int kb = kc * 16 + j * 4;
            if (dobn) {
                u0[j*4+0] = bnr1(As_[kb+0], Bb_[kb+0], h0.x);
                u0[j*4+1] = bnr1(As_[kb+1], Bb_[kb+1], h0.y);
                u0[j*4+2] = bnr1(As_[kb+2], Bb_[kb+2], h0.z);
                u0[j*4+3] = bnr1(As_[kb+3], Bb_[kb+3], h0.w);
                u1[j*4+0] = bnr1(As_[kb+0], Bb_[kb+0], h1.x);
                u1[j*4+1] = bnr1(As_[kb+1], Bb_[kb+1], h1.y);
                u1[j*4+2] = bnr1(As_[kb+2], Bb_[kb+2], h1.z);
                u1[j*4+3] = bnr1(As_[kb+3], Bb_[kb+3], h1.w);
            } else {
                u0[j*4+0] = h0.x; u0[j*4+1] = h0.y; u0[j*4+2] = h0.z; u0[j*4+3] = h0.w;
                u1[j*4+0] = h1.x; u1[j*4+1] = h1.y; u1[j*4+2] = h1.z; u1[j*4+3] = h1.w;
            }
        }
#pragma unroll
        for (int k = 0; k < 16; ++k) {
            int kk = kc * 16 + k;
            float a0 = u0[k], a1 = u1[k];
#pragma unroll
            for (int c = 0; c < 4; ++c) {
                float4 bv = Bs[kk][ch * 4 + c];
                acc0[c].x += a0 * bv.x; acc0[c].y += a0 * bv.y;
                acc0[c].z += a0 * bv.z; acc0[c].w += a0 * bv.w;
                acc1[c].x += a1 * bv.x; acc1[c].y += a1 * bv.y;
                acc1[c].z += a1 * bv.z; acc1[c].w += a1 * bv.w;
            }
        }
    }
    float4* o0 = Out + (size_t)row0 * 16 + ch * 4;
#pragma unroll
    for (int c = 0; c < 4; ++c) o0[c] = acc0[c];
    if (r1ok) {
        float4* o1 = Out + (size_t)(row0 + 1) * 16 + ch * 4;
#pragma unroll
        for (int c = 0; c < 4; ++c) o1[c] = acc1[c];
    }
}

// -------- column stats: S[0..63]=sum, S[64..127]=sumsq ----------------------
__global__ __launch_bounds__(256) void k_stats(const float4* __restrict__ V,
        float* __restrict__ S, int M)
{
    int tid = threadIdx.x;
    int q = tid & 15, rs = tid >> 4;
    float4 sum = make_float4(0.f, 0.f, 0.f, 0.f);
    float4 ss = make_float4(0.f, 0.f, 0.f, 0.f);
    for (int r = blockIdx.x * 16 + rs; r < M; r += gridDim.x * 16) {
        float4 v = V[(size_t)r * 16 + q];
        sum.x += v.x; sum.y += v.y; sum.z += v.z; sum.w += v.w;
        ss.x += v.x * v.x; ss.y += v.y * v.y; ss.z += v.z * v.z; ss.w += v.w * v.w;
    }
    sum.x += __shfl_xor(sum.x, 16); sum.y += __shfl_xor(sum.y, 16);
    sum.z += __shfl_xor(sum.z, 16); sum.w += __shfl_xor(sum.w, 16);
    ss.x += __shfl_xor(ss.x, 16);   ss.y += __shfl_xor(ss.y, 16);
    ss.z += __shfl_xor(ss.z, 16);   ss.w += __shfl_xor(ss.w, 16);
    sum.x += __shfl_xor(sum.x, 32); sum.y += __shfl_xor(sum.y, 32);
    sum.z += __shfl_xor(sum.z, 32); sum.w += __shfl_xor(sum.w, 32);
    ss.x += __shfl_xor(ss.x, 32);   ss.y += __shfl_xor(ss.y, 32);
    ss.z += __shfl_xor(ss.z, 32);   ss.w += __shfl_xor(ss.w, 32);

    __shared__ float4 LS[4][16];
    __shared__ float4 LQ[4][16];
    int wave = tid >> 6, lane = tid & 63;
    if (lane < 16) { LS[wave][lane] = sum; LQ[wave][lane] = ss; }
    __syncthreads();
    if (tid < 16) {
        float4 s0 = LS[0][tid], q0 = LQ[0][tid];
#pragma unroll
        for (int w = 1; w < 4; ++w) {
            float4 sw = LS[w][tid], qw = LQ[w][tid];
            s0.x += sw.x; s0.y += sw.y; s0.z += sw.z; s0.w += sw.w;
            q0.x += qw.x; q0.y += qw.y; q0.z += qw.z; q0.w += qw.w;
        }
        atomicAdd4(S + tid * 4, s0);
        atomicAdd4(S + 64 + tid * 4, q0);
    }
}

// -------- per-graph mean pool with BN2+ReLU fused on read -------------------
__global__ __launch_bounds__(256) void k_pool(const float4* __restrict__ H,
        const int* __restrict__ batch, const float* __restrict__ Sin,
        const float* __restrict__ g, const float* __restrict__ bt,
        float* __restrict__ POOL, float* __restrict__ CNT,
        int M, int chunk, float invM)
{
    int q = threadIdx.x & 15, rs = threadIdx.x >> 4;
    float as[4], bs[4];
#pragma unroll
    for (int j = 0; j < 4; ++j) {
        int c = q * 4 + j;
        float mu = Sin[c] * invM;
        float var = Sin[64 + c] * invM - mu * mu;
        float a = g[c] * rsqrtf(var + BN_EPS);
        as[j] = a;
        bs[j] = bt[c] - a * mu;
    }
    int start = blockIdx.x * chunk;
    int end = min(M, start + chunk);
    int curg = -1;
    float4 acc = make_float4(0.f, 0.f, 0.f, 0.f);
    float cl = 0.f;
    for (int r = start + rs; r < end; r += 16) {
        int gg = batch[r];
        float4 v = H[(size_t)r * 16 + q];
        v.x = bnr1(as[0], bs[0], v.x); v.y = bnr1(as[1], bs[1], v.y);
        v.z = bnr1(as[2], bs[2], v.z); v.w = bnr1(as[3], bs[3], v.w);
        if (gg != curg) {
            if (curg >= 0) {
                atomicAdd4(POOL + (size_t)curg * 64 + q * 4, acc);
                if (q == 0) unsafeAtomicAdd(CNT + curg, cl);
            }
            curg = gg;
            acc = make_float4(0.f, 0.f, 0.f, 0.f);
            cl = 0.f;
        }
        acc.x += v.x; acc.y += v.y; acc.z += v.z; acc.w += v.w;
        cl += 1.f;
    }
    if (curg >= 0) {
        atomicAdd4(POOL + (size_t)curg * 64 + q * 4, acc);
        if (q == 0) unsafeAtomicAdd(CNT + curg, cl);
    }
}

// -------- head --------------------------------------------------------------
__global__ __launch_bounds__(256) void k_head(const float* __restrict__ POOL,
        const float* __restrict__ CNT, const float* __restrict__ Wh,
        const float* __restrict__ bh, float* __restrict__ OUT, int ngraph)
{
    int lane = threadIdx.x & 63;
    int wv = threadIdx.x >> 6;
    int gidx = blockIdx.x * 4 + wv;
    if (gidx >= ngraph) return;
    float c = fmaxf(CNT[gidx], 1.0f);
    float v = POOL[(size_t)gidx * 64 + lane] / c * Wh[lane];
#pragma unroll
    for (int off = 1; off < 64; off <<= 1) v += __shfl_xor(v, off);
    if (lane == 0) OUT[gidx] = v + bh[0];
}

extern "C" void kernel_launch(void* const* d_in, const int* in_sizes, int n_in,
                              void* d_out, int out_size, void* d_ws, size_t ws_size,
                              hipStream_t stream)
{
    const float* x   = (const float*)d_in[0];
    const int*   ei  = (const int*)d_in[1];
    const int*   bat = (const int*)d_in[2];
    const float* W1  = (const float*)d_in[3];
    const float* b1  = (const float*)d_in[4];
    const float* g1  = (const float*)d_in[5];
    const float* bt1 = (const float*)d_in[6];
    const float* W2  = (const float*)d_in[7];
    const float* b2  = (const float*)d_in[8];
    const float* g2  = (const float*)d_in[9];
    const float* bt2 = (const float*)d_in[10];
    const float* eps = (const float*)d_in[11];
    const float* Wh  = (const float*)d_in[12];
    const float* bh  = (const float*)d_in[13];
    float* out = (float*)d_out;

    int M = in_sizes[0] / 64;
    int nedges = in_sizes[1] / 2;
    const int* src = ei;
    const int* dst = ei + nedges;
    const int NG = 512;
    float invM = 1.0f / (float)M;

    float* ws = (float*)d_ws;
    size_t NE = (size_t)M * 64;
    float* P0   = ws;               // U/Z ping
    float* P1   = ws + NE;          // U/Z pong
    float* V    = ws + 2 * NE;
    float* S1   = ws + 3 * NE;      // 4 layers x 128
    float* S2   = S1 + 512;
    float* POOL = S2 + 512;         // 512 x 64
    float* CNT  = POOL + (size_t)NG * 64;  // 512

    int* rowptr = (int*)(CNT + NG);        // M+1
    int* fillp  = rowptr + (M + 1);        // M
    int* deg    = fillp + M;               // M
    int* incl   = deg + M;                 // M
    int* bsum   = incl + M;                // 512
    int* csr    = bsum + 512;              // nedges

    hipMemsetAsync(deg, 0, (size_t)M * sizeof(int), stream);
    hipMemsetAsync(S1, 0, (512 + 512 + (size_t)NG * 64 + NG) * sizeof(float), stream);

    int edgeGrid = (nedges + 255) / 256;

    // ---- CSR build ----
    k_count<<<edgeGrid, 256, 0, stream>>>(dst, deg, nedges);
    int NB = (M + 255) / 256;
    k_scanA<<<NB, 256, 0, stream>>>(deg, incl, bsum, M);
    k_scanB<<<1, 512, 0, stream>>>(bsum, NB);
    k_scanC<<<NB, 256, 0, stream>>>(deg, incl, bsum, rowptr, fillp, M);
    k_fill<<<edgeGrid, 256, 0, stream>>>(src, dst, fillp, csr, nedges);

    int gemmGrid = (M + 127) / 128;
    int gatherGrid = (M + 3) / 4;

    const float* prevZ = x;
    for (int i = 0; i < 4; ++i) {
        float* Ub = (i & 1) ? P1 : P0;
        const float* Sprev = (i == 0) ? nullptr : (S2 + (size_t)(i - 1) * 128);
        const float* gprev = (i == 0) ? g2 : (g2 + (size_t)(i - 1) * 64);
        const float* bprev = (i == 0) ? bt2 : (bt2 + (size_t)(i - 1) * 64);

        k_gather<<<gatherGrid, 256, 0, stream>>>((const float4*)prevZ, rowptr, csr,
                Sprev, gprev, bprev, eps, i, (float4*)Ub, M, invM);
        k_gemm<<<gemmGrid, 256, 0, stream>>>((const float4*)Ub, nullptr, g1, bt1,
                W1 + (size_t)i * 4096, b1 + i * 64, (float4*)V, M);
        k_stats<<<400, 256, 0, stream>>>((const float4*)V, S1 + (size_t)i * 128, M);
        k_gemm<<<gemmGrid, 256, 0, stream>>>((const float4*)V, S1 + (size_t)i * 128,
                g1 + i * 64, bt1 + i * 64, W2 + (size_t)i * 4096, b2 + i * 64,
                (float4*)Ub, M);   // Z overwrites U (dead)
        k_stats<<<400, 256, 0, stream>>>((const float4*)Ub, S2 + (size_t)i * 128, M);
        prevZ = Ub;
    }
    int chunk = (M + 511) / 512;
    k_pool<<<512, 256, 0, stream>>>((const float4*)prevZ, bat, S2 + 3 * 128,
            g2 + 192, bt2 + 192, POOL, CNT, M, chunk, invM);
    k_head<<<(NG + 3) / 4, 256, 0, stream>>>(POOL, CNT, Wh, bh, out, NG);
}

// Round 6
// 746.140 us; speedup vs baseline: 9.2662x; 1.4175x over previous
//
#include <hip/hip_runtime.h>

#define BN_EPS 1e-5f

__device__ __forceinline__ void atomicAdd4(float* p, float4 v) {
    unsafeAtomicAdd(p + 0, v.x);
    unsafeAtomicAdd(p + 1, v.y);
    unsafeAtomicAdd(p + 2, v.z);
    unsafeAtomicAdd(p + 3, v.w);
}

__device__ __forceinline__ float bnr1(float a, float b, float v) {
    return fmaxf(fmaf(a, v, b), 0.0f);
}

// ===================== CSR build (once, reused for all 4 layers) ============
// XCD-partitioned: block b -> XCD slot (b&7) owns dst range [M*x/8, M*(x+1)/8);
// block scans its edge chunk, acts only on in-range dst. Each csr/deg line is
// then dirtied by ONE XCD -> writebacks ~6.4MB instead of 8x. Pure locality
// hint: correct under any blockIdx->XCD mapping.

__global__ __launch_bounds__(256) void k_count(const int* __restrict__ dst,
        int* __restrict__ deg, int nedges, int M)
{
    int nx = gridDim.x >> 3;
    int x  = blockIdx.x & 7;
    int ci = blockIdx.x >> 3;
    int lo = (int)(((long long)M * x) >> 3);
    int hi = (int)(((long long)M * (x + 1)) >> 3);
    int chunk = (nedges + nx - 1) / nx;
    int e0 = ci * chunk;
    int e1 = min(nedges, e0 + chunk);
    for (int e = e0 + threadIdx.x; e < e1; e += 256) {
        int d = dst[e];
        if (d >= lo && d < hi) atomicAdd(&deg[d], 1);
    }
}

__global__ __launch_bounds__(256) void k_scanA(const int* __restrict__ deg,
        int* __restrict__ incl, int* __restrict__ bsum, int N)
{
    __shared__ int tmp[256];
    int i = blockIdx.x * 256 + threadIdx.x;
    int d = (i < N) ? deg[i] : 0;
    tmp[threadIdx.x] = d;
    __syncthreads();
    for (int off = 1; off < 256; off <<= 1) {
        int val = (threadIdx.x >= off) ? tmp[threadIdx.x - off] : 0;
        __syncthreads();
        tmp[threadIdx.x] += val;
        __syncthreads();
    }
    if (i < N) incl[i] = tmp[threadIdx.x];
    if (threadIdx.x == 255) bsum[blockIdx.x] = tmp[255];
}

__global__ __launch_bounds__(512) void k_scanB(int* __restrict__ bsum, int NB)
{
    __shared__ int tmp[512];
    int tid = threadIdx.x;
    int d = (tid < NB) ? bsum[tid] : 0;
    tmp[tid] = d;
    __syncthreads();
    for (int off = 1; off < 512; off <<= 1) {
        int val = (tid >= off) ? tmp[tid - off] : 0;
        __syncthreads();
        tmp[tid] += val;
        __syncthreads();
    }
    if (tid < NB) bsum[tid] = tmp[tid] - d;   // exclusive
}

__global__ __launch_bounds__(256) void k_scanC(const int* __restrict__ deg,
        const int* __restrict__ incl, const int* __restrict__ bsum,
        int* __restrict__ rowptr, int* __restrict__ fill, int N)
{
    int i = blockIdx.x * 256 + threadIdx.x;
    if (i >= N) return;
    int d = deg[i];
    int excl = incl[i] - d + bsum[blockIdx.x];
    rowptr[i] = excl;
    fill[i] = excl;
    if (i == N - 1) rowptr[N] = excl + d;
}

__global__ __launch_bounds__(256) void k_fill(const int* __restrict__ src,
        const int* __restrict__ dst, int* __restrict__ fillp,
        int* __restrict__ csr, int nedges, int M)
{
    int nx = gridDim.x >> 3;
    int x  = blockIdx.x & 7;
    int ci = blockIdx.x >> 3;
    int lo = (int)(((long long)M * x) >> 3);
    int hi = (int)(((long long)M * (x + 1)) >> 3);
    int chunk = (nedges + nx - 1) / nx;
    int e0 = ci * chunk;
    int e1 = min(nedges, e0 + chunk);
    for (int e = e0 + threadIdx.x; e < e1; e += 256) {
        int d = dst[e];
        if (d >= lo && d < hi) {
            int pos = atomicAdd(&fillp[d], 1);
            csr[pos] = src[e];
        }
    }
}

// ===================== gather: BN2(prev)+ReLU fused on read =================
// U[d] = (1+eps)*val(d) + sum_{s in adj(d)} val(s); val = relu(a*Z+b) or raw x.
// wave = 1 node; 16 edges per inner step -> 4 independent loads/lane in
// flight. All control flow around __shfl is wave-uniform; shuffle source
// lanes clamped to lane 0 (always valid); accumulate predicated.
__global__ __launch_bounds__(256) void k_gather(const float4* __restrict__ H,
        const int* __restrict__ rowptr, const int* __restrict__ csr,
        const float* __restrict__ Sin, const float* __restrict__ g,
        const float* __restrict__ bt, const float* __restrict__ epsp,
        int layer, float4* __restrict__ U, int N, float invM)
{
    int lane = threadIdx.x & 63;
    int wv = threadIdx.x >> 6;
    int node = blockIdx.x * 4 + wv;
    if (node >= N) return;
    int q = lane & 15, sub = lane >> 4;

    float4 A4 = make_float4(1.f, 1.f, 1.f, 1.f);
    float4 B4 = make_float4(0.f, 0.f, 0.f, 0.f);
    bool dobn = (Sin != nullptr);
    if (dobn) {
        float as[4], bs[4];
#pragma unroll
        for (int j = 0; j < 4; ++j) {
            int c = q * 4 + j;
            float mu = Sin[c] * invM;
            float var = Sin[64 + c] * invM - mu * mu;
            float a = g[c] * rsqrtf(var + BN_EPS);
            as[j] = a;
            bs[j] = bt[c] - a * mu;
        }
        A4 = make_float4(as[0], as[1], as[2], as[3]);
        B4 = make_float4(bs[0], bs[1], bs[2], bs[3]);
    }

    int start = rowptr[node], end = rowptr[node + 1];
    float4 acc = make_float4(0.f, 0.f, 0.f, 0.f);

    for (int base = start; base < end; base += 64) {
        int n = min(64, end - base);               // wave-uniform
        int myidx = (lane < n) ? csr[base + lane] : 0;
        int nIter = (n + 15) >> 4;                 // wave-uniform trip count
        for (int t = 0; t < nIter; ++t) {
            int j0 = t * 16 + sub;
            int j1 = j0 + 4, j2 = j0 + 8, j3 = j0 + 12;
            int s0 = __shfl(myidx, (j0 < n) ? j0 : 0);
            int s1 = __shfl(myidx, (j1 < n) ? j1 : 0);
            int s2 = __shfl(myidx, (j2 < n) ? j2 : 0);
            int s3 = __shfl(myidx, (j3 < n) ? j3 : 0);
            float4 v0 = H[(size_t)s0 * 16 + q];
            float4 v1 = H[(size_t)s1 * 16 + q];
            float4 v2 = H[(size_t)s2 * 16 + q];
            float4 v3 = H[(size_t)s3 * 16 + q];
            if (dobn) {
                v0.x = bnr1(A4.x, B4.x, v0.x); v0.y = bnr1(A4.y, B4.y, v0.y);
                v0.z = bnr1(A4.z, B4.z, v0.z); v0.w = bnr1(A4.w, B4.w, v0.w);
                v1.x = bnr1(A4.x, B4.x, v1.x); v1.y = bnr1(A4.y, B4.y, v1.y);
                v1.z = bnr1(A4.z, B4.z, v1.z); v1.w = bnr1(A4.w, B4.w, v1.w);
                v2.x = bnr1(A4.x, B4.x, v2.x); v2.y = bnr1(A4.y, B4.y, v2.y);
                v2.z = bnr1(A4.z, B4.z, v2.z); v2.w = bnr1(A4.w, B4.w, v2.w);
                v3.x = bnr1(A4.x, B4.x, v3.x); v3.y = bnr1(A4.y, B4.y, v3.y);
                v3.z = bnr1(A4.z, B4.z, v3.z); v3.w = bnr1(A4.w, B4.w, v3.w);
            }
            if (j0 < n) { acc.x += v0.x; acc.y += v0.y; acc.z += v0.z; acc.w += v0.w; }
            if (j1 < n) { acc.x += v1.x; acc.y += v1.y; acc.z += v1.z; acc.w += v1.w; }
            if (j2 < n) { acc.x += v2.x; acc.y += v2.y; acc.z += v2.z; acc.w += v2.w; }
            if (j3 < n) { acc.x += v3.x; acc.y += v3.y; acc.z += v3.z; acc.w += v3.w; }
        }
    }
    acc.x += __shfl_xor(acc.x, 16); acc.y += __shfl_xor(acc.y, 16);
    acc.z += __shfl_xor(acc.z, 16); acc.w += __shfl_xor(acc.w, 16);
    acc.x += __shfl_xor(acc.x, 32); acc.y += __shfl_xor(acc.y, 32);
    acc.z += __shfl_xor(acc.z, 32); acc.w += __shfl_xor(acc.w, 32);

    if (sub == 0) {
        float4 hv = H[(size_t)node * 16 + q];
        if (dobn) {
            hv.x = bnr1(A4.x, B4.x, hv.x); hv.y = bnr1(A4.y, B4.y, hv.y);
            hv.z = bnr1(A4.z, B4.z, hv.z); hv.w = bnr1(A4.w, B4.w, hv.w);
        }
        float e = 1.0f + epsp[layer];
        float4 o;
        o.x = fmaf(e, hv.x, acc.x); o.y = fmaf(e, hv.y, acc.y);
        o.z = fmaf(e, hv.z, acc.z); o.w = fmaf(e, hv.w, acc.w);
        U[(size_t)node * 16 + q] = o;
    }
}

// ===================== GEMM + fused column stats ============================
// Out[r][c] = sum_k f(In[r][k]) * W[k][c] + bias[c],  f = relu(a*v+b) or id
// Sout[0..63] += column sums, Sout[64..127] += column sumsq (for next BN).
// 2 rows x 16 cols per thread; NO early return (all threads reach shuffles);
// out-of-range rows clamp pointers, zero stats, skip store. kc loop not
// unrolled (R4 lesson: full unroll -> 256 VGPR + scratch spill).
__global__ __launch_bounds__(256) void k_gemm(const float4* __restrict__ In,
        const float* __restrict__ Sin, const float* __restrict__ g,
        const float* __restrict__ bt, const float* __restrict__ W,
        const float* __restrict__ bias, float4* __restrict__ Out,
        float* __restrict__ Sout, int M)
{
    __shared__ float4 Bs[64][16];   // W tile, 16 KB
    __shared__ float As_[64];
    __shared__ float Bb_[64];
    __shared__ float SRED[4][128];
    int tid = threadIdx.x;
    const float4* W4 = (const float4*)W;
#pragma unroll
    for (int i = 0; i < 4; ++i)
        ((float4*)Bs)[tid + 256 * i] = W4[tid + 256 * i];
    if (tid < 64) {
        if (Sin) {
            float invM = 1.0f / (float)M;
            float mu = Sin[tid] * invM;
            float var = Sin[64 + tid] * invM - mu * mu;
            float a = g[tid] * rsqrtf(var + BN_EPS);
            As_[tid] = a;
            Bb_[tid] = bt[tid] - a * mu;
        } else { As_[tid] = 1.f; Bb_[tid] = 0.f; }
    }
    __syncthreads();

    int ch = tid & 3;              // col group: float4 cols [ch*4, ch*4+4)
    int rp = tid >> 2;             // row pair index 0..63
    int row0 = blockIdx.x * 128 + rp * 2;
    bool v0 = row0 < M;
    bool v1 = (row0 + 1) < M;
    bool dobn = (Sin != nullptr);

    const float4* p0 = In + (size_t)(v0 ? row0 : 0) * 16;
    const float4* p1 = In + (size_t)(v1 ? row0 + 1 : 0) * 16;

    float4 acc0[4], acc1[4];
    const float4* b4 = (const float4*)bias;
#pragma unroll
    for (int c = 0; c < 4; ++c) { acc0[c] = b4[ch * 4 + c]; acc1[c] = acc0[c]; }

#pragma unroll 1
    for (int kc = 0; kc < 4; ++kc) {
        float u0[16], u1[16];
#pragma unroll
        for (int j = 0; j < 4; ++j) {
            float4 h0 = p0[kc * 4 + j];
            float4 h1 = p1[kc * 4 + j];
            int kb = kc * 16 + j * 4;
            if (dobn) {
                u0[j*4+0] = bnr1(As_[kb+0], Bb_[kb+0], h0.x);
                u0[j*4+1] = bnr1(As_[kb+1], Bb_[kb+1], h0.y);
                u0[j*4+2] = bnr1(As_[kb+2], Bb_[kb+2], h0.z);
                u0[j*4+3] = bnr1(As_[kb+3], Bb_[kb+3], h0.w);
                u1[j*4+0] = bnr1(As_[kb+0], Bb_[kb+0], h1.x);
                u1[j*4+1] = bnr1(As_[kb+1], Bb_[kb+1], h1.y);
                u1[j*4+2] = bnr1(As_[kb+2], Bb_[kb+2], h1.z);
                u1[j*4+3] = bnr1(As_[kb+3], Bb_[kb+3], h1.w);
            } else {
                u0[j*4+0] = h0.x; u0[j*4+1] = h0.y; u0[j*4+2] = h0.z; u0[j*4+3] = h0.w;
                u1[j*4+0] = h1.x; u1[j*4+1] = h1.y; u1[j*4+2] = h1.z; u1[j*4+3] = h1.w;
            }
        }
#pragma unroll
        for (int k = 0; k < 16; ++k) {
            int kk = kc * 16 + k;
            float a0 = u0[k], a1 = u1[k];
#pragma unroll
            for (int c = 0; c < 4; ++c) {
                float4 bv = Bs[kk][ch * 4 + c];
                acc0[c].x += a0 * bv.x; acc0[c].y += a0 * bv.y;
                acc0[c].z += a0 * bv.z; acc0[c].w += a0 * bv.w;
                acc1[c].x += a1 * bv.x; acc1[c].y += a1 * bv.y;
                acc1[c].z += a1 * bv.z; acc1[c].w += a1 * bv.w;
            }
        }
    }
    if (v0) {
        float4* o0 = Out + (size_t)row0 * 16 + ch * 4;
#pragma unroll
        for (int c = 0; c < 4; ++c) o0[c] = acc0[c];
    }
    if (v1) {
        float4* o1 = Out + (size_t)(row0 + 1) * 16 + ch * 4;
#pragma unroll
        for (int c = 0; c < 4; ++c) o1[c] = acc1[c];
    }

    // ---- fused column stats ----
    float4 zero = make_float4(0.f, 0.f, 0.f, 0.f);
    if (!v0) { acc0[0] = zero; acc0[1] = zero; acc0[2] = zero; acc0[3] = zero; }
    if (!v1) { acc1[0] = zero; acc1[1] = zero; acc1[2] = zero; acc1[3] = zero; }
    float4 s4[4], q4[4];
#pragma unroll
    for (int c = 0; c < 4; ++c) {
        s4[c].x = acc0[c].x + acc1[c].x; s4[c].y = acc0[c].y + acc1[c].y;
        s4[c].z = acc0[c].z + acc1[c].z; s4[c].w = acc0[c].w + acc1[c].w;
        q4[c].x = acc0[c].x * acc0[c].x + acc1[c].x * acc1[c].x;
        q4[c].y = acc0[c].y * acc0[c].y + acc1[c].y * acc1[c].y;
        q4[c].z = acc0[c].z * acc0[c].z + acc1[c].z * acc1[c].z;
        q4[c].w = acc0[c].w * acc0[c].w + acc1[c].w * acc1[c].w;
    }
    // butterfly across the wave's 16 same-ch threads (lane xor 4,8,16,32)
#pragma unroll
    for (int off = 4; off < 64; off <<= 1) {
#pragma unroll
        for (int c = 0; c < 4; ++c) {
            s4[c].x += __shfl_xor(s4[c].x, off); s4[c].y += __shfl_xor(s4[c].y, off);
            s4[c].z += __shfl_xor(s4[c].z, off); s4[c].w += __shfl_xor(s4[c].w, off);
            q4[c].x += __shfl_xor(q4[c].x, off); q4[c].y += __shfl_xor(q4[c].y, off);
            q4[c].z += __shfl_xor(q4[c].z, off); q4[c].w += __shfl_xor(q4[c].w, off);
        }
    }
    int wave = tid >> 6, lane = tid & 63;
    if (lane < 4) {   // lane == ch here
#pragma unroll
        for (int c = 0; c < 4; ++c) {
            int cb = lane * 16 + c * 4;
            SRED[wave][cb + 0] = s4[c].x; SRED[wave][cb + 1] = s4[c].y;
            SRED[wave][cb + 2] = s4[c].z; SRED[wave][cb + 3] = s4[c].w;
            SRED[wave][64 + cb + 0] = q4[c].x; SRED[wave][64 + cb + 1] = q4[c].y;
            SRED[wave][64 + cb + 2] = q4[c].z; SRED[wave][64 + cb + 3] = q4[c].w;
        }
    }
    __syncthreads();
    if (tid < 128) {
        float v = SRED[0][tid] + SRED[1][tid] + SRED[2][tid] + SRED[3][tid];
        unsafeAtomicAdd(&Sout[tid], v);
    }
}

// -------- per-graph mean pool with BN2+ReLU fused on read -------------------
__global__ __launch_bounds__(256) void k_pool(const float4* __restrict__ H,
        const int* __restrict__ batch, const float* __restrict__ Sin,
        const float* __restrict__ g, const float* __restrict__ bt,
        float* __restrict__ POOL, float* __restrict__ CNT,
        int M, int chunk, float invM)
{
    int q = threadIdx.x & 15, rs = threadIdx.x >> 4;
    float as[4], bs[4];
#pragma unroll
    for (int j = 0; j < 4; ++j) {
        int c = q * 4 + j;
        float mu = Sin[c] * invM;
        float var = Sin[64 + c] * invM - mu * mu;
        float a = g[c] * rsqrtf(var + BN_EPS);
        as[j] = a;
        bs[j] = bt[c] - a * mu;
    }
    int start = blockIdx.x * chunk;
    int end = min(M, start + chunk);
    int curg = -1;
    float4 acc = make_float4(0.f, 0.f, 0.f, 0.f);
    float cl = 0.f;
    for (int r = start + rs; r < end; r += 16) {
        int gg = batch[r];
        float4 v = H[(size_t)r * 16 + q];
        v.x = bnr1(as[0], bs[0], v.x); v.y = bnr1(as[1], bs[1], v.y);
        v.z = bnr1(as[2], bs[2], v.z); v.w = bnr1(as[3], bs[3], v.w);
        if (gg != curg) {
            if (curg >= 0) {
                atomicAdd4(POOL + (size_t)curg * 64 + q * 4, acc);
                if (q == 0) unsafeAtomicAdd(CNT + curg, cl);
            }
            curg = gg;
            acc = make_float4(0.f, 0.f, 0.f, 0.f);
            cl = 0.f;
        }
        acc.x += v.x; acc.y += v.y; acc.z += v.z; acc.w += v.w;
        cl += 1.f;
    }
    if (curg >= 0) {
        atomicAdd4(POOL + (size_t)curg * 64 + q * 4, acc);
        if (q == 0) unsafeAtomicAdd(CNT + curg, cl);
    }
}

// -------- head --------------------------------------------------------------
__global__ __launch_bounds__(256) void k_head(const float* __restrict__ POOL,
        const float* __restrict__ CNT, const float* __restrict__ Wh,
        const float* __restrict__ bh, float* __restrict__ OUT, int ngraph)
{
    int lane = threadIdx.x & 63;
    int wv = threadIdx.x >> 6;
    int gidx = blockIdx.x * 4 + wv;
    if (gidx >= ngraph) return;
    float c = fmaxf(CNT[gidx], 1.0f);
    float v = POOL[(size_t)gidx * 64 + lane] / c * Wh[lane];
#pragma unroll
    for (int off = 1; off < 64; off <<= 1) v += __shfl_xor(v, off);
    if (lane == 0) OUT[gidx] = v + bh[0];
}

extern "C" void kernel_launch(void* const* d_in, const int* in_sizes, int n_in,
                              void* d_out, int out_size, void* d_ws, size_t ws_size,
                              hipStream_t stream)
{
    const float* x   = (const float*)d_in[0];
    const int*   ei  = (const int*)d_in[1];
    const int*   bat = (const int*)d_in[2];
    const float* W1  = (const float*)d_in[3];
    const float* b1  = (const float*)d_in[4];
    const float* g1  = (const float*)d_in[5];
    const float* bt1 = (const float*)d_in[6];
    const float* W2  = (const float*)d_in[7];
    const float* b2  = (const float*)d_in[8];
    const float* g2  = (const float*)d_in[9];
    const float* bt2 = (const float*)d_in[10];
    const float* eps = (const float*)d_in[11];
    const float* Wh  = (const float*)d_in[12];
    const float* bh  = (const float*)d_in[13];
    float* out = (float*)d_out;

    int M = in_sizes[0] / 64;
    int nedges = in_sizes[1] / 2;
    const int* src = ei;
    const int* dst = ei + nedges;
    const int NG = 512;
    float invM = 1.0f / (float)M;

    float* ws = (float*)d_ws;
    size_t NE = (size_t)M * 64;
    float* P0   = ws;               // U/Z ping
    float* P1   = ws + NE;          // U/Z pong
    float* V    = ws + 2 * NE;
    float* S1   = ws + 3 * NE;      // 4 layers x 128
    float* S2   = S1 + 512;
    float* POOL = S2 + 512;         // 512 x 64
    float* CNT  = POOL + (size_t)NG * 64;  // 512

    int* rowptr = (int*)(CNT + NG);        // M+1
    int* fillp  = rowptr + (M + 1);        // M
    int* deg    = fillp + M;               // M
    int* incl   = deg + M;                 // M
    int* bsum   = incl + M;                // 512
    int* csr    = bsum + 512;              // nedges

    hipMemsetAsync(deg, 0, (size_t)M * sizeof(int), stream);
    hipMemsetAsync(S1, 0, (512 + 512 + (size_t)NG * 64 + NG) * sizeof(float), stream);

    // ---- CSR build (XCD-partitioned count + fill) ----
    k_count<<<1024, 256, 0, stream>>>(dst, deg, nedges, M);
    int NB = (M + 255) / 256;
    k_scanA<<<NB, 256, 0, stream>>>(deg, incl, bsum, M);
    k_scanB<<<1, 512, 0, stream>>>(bsum, NB);
    k_scanC<<<NB, 256, 0, stream>>>(deg, incl, bsum, rowptr, fillp, M);
    k_fill<<<1024, 256, 0, stream>>>(src, dst, fillp, csr, nedges, M);

    int gemmGrid = (M + 127) / 128;
    int gatherGrid = (M + 3) / 4;

    const float* prevZ = x;
    for (int i = 0; i < 4; ++i) {
        float* Ub = (i & 1) ? P1 : P0;
        const float* Sprev = (i == 0) ? nullptr : (S2 + (size_t)(i - 1) * 128);
        const float* gprev = (i == 0) ? g2 : (g2 + (size_t)(i - 1) * 64);
        const float* bprev = (i == 0) ? bt2 : (bt2 + (size_t)(i - 1) * 64);

        k_gather<<<gatherGrid, 256, 0, stream>>>((const float4*)prevZ, rowptr, csr,
                Sprev, gprev, bprev, eps, i, (float4*)Ub, M, invM);
        k_gemm<<<gemmGrid, 256, 0, stream>>>((const float4*)Ub, nullptr, g1, bt1,
                W1 + (size_t)i * 4096, b1 + i * 64, (float4*)V,
                S1 + (size_t)i * 128, M);
        k_gemm<<<gemmGrid, 256, 0, stream>>>((const float4*)V, S1 + (size_t)i * 128,
                g1 + i * 64, bt1 + i * 64, W2 + (size_t)i * 4096, b2 + i * 64,
                (float4*)Ub, S2 + (size_t)i * 128, M);   // Z overwrites U (dead)
        prevZ = Ub;
    }
    int chunk = (M + 511) / 512;
    k_pool<<<512, 256, 0, stream>>>((const float4*)prevZ, bat, S2 + 3 * 128,
            g2 + 192, bt2 + 192, POOL, CNT, M, chunk, invM);
    k_head<<<(NG + 3) / 4, 256, 0, stream>>>(POOL, CNT, Wh, bh, out, NG);
}